// Round 6
// baseline (294.358 us; speedup 1.0000x reference)
//
#include <hip/hip_runtime.h>

// BoundaryFocalLoss: B=128, T=200000, f32 inputs, i32 targets, f32 mask -> scalar f32.
//
// R1: 654 us = same-address atomic serialization -> partials (124 us).
// R2-R5 post-mortem: three different register-load kernels all hit
//   dur == FETCH_SIZE / ~1.3 TB/s (R2 1.27, R3 1.27, R4 1.36 TB/s) with VALU-busy
//   invariant ~40 us -> outstanding-read-depth wall: register-destination loads
//   can't keep enough misses in flight (VGPR-bound: R3 serialized at 28 VGPR,
//   R5 occupancy-collapsed at 120 VGPR, R4 spilled under a cap).
// R6: async global->LDS DMA (global_load_lds w=16): load depth decoupled from
//   VGPRs. Per-wave private double buffers, NO __syncthreads in loop, manual
//   s_waitcnt vmcnt(7) via asm (memory clobber = compiler fence). 768 blocks =
//   exactly 3 blocks/CU at 50KB LDS; 12 waves/CU x ~6.3KB in flight each.

#define B_DIM 128
#define T_DIM 200000

constexpr int BLOCK         = 256;                    // 4 waves
constexpr int TW            = 512;                    // elems per wave-tile
constexpr int TILES_PER_ROW = (T_DIM + TW - 1) / TW;  // 391 (tile 390 partial)
constexpr int WAVES_PER_ROW = 24;
constexpr int GRID          = B_DIM * WAVES_PER_ROW / 4;  // 768 blocks
constexpr int NUM_PARTIALS  = GRID;

__device__ __forceinline__ void dma16(const void* g, void* l) {
    __builtin_amdgcn_global_load_lds(
        (const __attribute__((address_space(1))) void*)g,
        (__attribute__((address_space(3))) void*)l, 16, 0, 0);
}
__device__ __forceinline__ void dma4(const void* g, void* l) {
    __builtin_amdgcn_global_load_lds(
        (const __attribute__((address_space(1))) void*)g,
        (__attribute__((address_space(3))) void*)l, 4, 0, 0);
}

__global__ __launch_bounds__(BLOCK) void bfl_main(
    const float* __restrict__ inputs,
    const int*   __restrict__ targets,
    const float* __restrict__ mask,
    float2*      __restrict__ partials)
{
    // Per-wave private double buffers: 2 x 4 waves x (2KB x + 2KB m + 2KB t + 256B halo) = 50KB
    __shared__ __align__(16) float s_x[2][4][TW];
    __shared__ __align__(16) float s_m[2][4][TW];
    __shared__ __align__(16) int   s_t[2][4][TW];
    __shared__ __align__(16) int   s_h[2][4][64];

    const int wv   = threadIdx.x >> 6;
    const int lane = threadIdx.x & 63;
    const int gw   = blockIdx.x * 4 + wv;          // global wave id [0, 3072)
    const int row  = gw / WAVES_PER_ROW;           // [0, 128)
    const int widx = gw % WAVES_PER_ROW;           // [0, 24)

    const long long roff = (long long)row * T_DIM;
    const float* __restrict__ pi = inputs  + roff;
    const float* __restrict__ pm = mask    + roff;
    const int*   __restrict__ pt = targets + roff;

    // Issue one tile's staging: 6x dma16 + 1x dma4 = 7 vmem ops.
    // Per-lane source addresses clamped to the row (OOB-safe); garbage staged
    // for tail lanes is zeroed at compute via nvld / bit-mask.
    auto issue = [&](int E, int d) {
        #pragma unroll
        for (int j = 0; j < 2; ++j) {
            int e0 = E + j * 256 + lane * 4;
            e0 = (e0 > T_DIM - 4) ? (T_DIM - 4) : e0;
            dma16(pi + e0, &s_x[d][wv][j * 256]);
            dma16(pm + e0, &s_m[d][wv][j * 256]);
            dma16(pt + e0, &s_t[d][wv][j * 256]);
        }
        // halo: lanes 0-3 -> targets[E-4..E-1] (clamped to 0 at row start ->
        // replicate targets[0], which zeroes edge trans bits = reference pad);
        // lanes 4-6 -> targets[E+512..E+514] (clamped to row end).
        int he = (lane < 4) ? (E - 4 + lane)
               : (lane < 7) ? (E + TW + (lane - 4))
               : 0;
        he = (he < 0) ? 0 : ((he > T_DIM - 1) ? (T_DIM - 1) : he);
        dma4(pt + he, &s_h[d][wv][0]);
    };

    float lsum = 0.0f, msum = 0.0f;

    int t = widx;
    int d = 0;
    issue(t * TW, 0);

    while (true) {
        const int  tn  = t + WAVES_PER_ROW;
        const bool has = (tn < TILES_PER_ROW);
        if (has) {
            issue(tn * TW, d ^ 1);
            // retire the previous tile's 7 ops; keep this iter's 7 in flight
            __asm__ volatile("s_waitcnt vmcnt(7)" ::: "memory");
        } else {
            __asm__ volatile("s_waitcnt vmcnt(0)" ::: "memory");
        }

        // ---- compute tile t from buffer d ----
        const int E = t * TW;
        const int e = E + lane * 8;

        const float4 x0 = *(const float4*)&s_x[d][wv][lane * 8];
        const float4 x1 = *(const float4*)&s_x[d][wv][lane * 8 + 4];
        const float4 m0 = *(const float4*)&s_m[d][wv][lane * 8];
        const float4 m1 = *(const float4*)&s_m[d][wv][lane * 8 + 4];
        const int4   c0 = *(const int4*)&s_t[d][wv][lane * 8];
        const int4   c1 = *(const int4*)&s_t[d][wv][lane * 8 + 4];
        const int4   hv0 = *(const int4*)&s_h[d][wv][0];   // prev 4 targets
        const int4   hv1 = *(const int4*)&s_h[d][wv][4];   // next 3 targets (+1 pad)

        // inter-lane halo via shfl (lane 0 / 63 patched from the DMA'd halo)
        int pe0 = __shfl_up(c1.x, 1), pe1 = __shfl_up(c1.y, 1);
        int pe2 = __shfl_up(c1.z, 1), pe3 = __shfl_up(c1.w, 1);
        int ne0 = __shfl_down(c0.x, 1), ne1 = __shfl_down(c0.y, 1), ne2 = __shfl_down(c0.z, 1);
        if (lane == 0)  { pe0 = hv0.x; pe1 = hv0.y; pe2 = hv0.z; pe3 = hv0.w; }
        if (lane == 63) { ne0 = hv1.x; ne1 = hv1.y; ne2 = hv1.z; }

        // transition bits: bit k <-> trans at j = e - 4 + k, k = 1..14
        unsigned mb = 0u;
        mb |= (pe1  != pe0 ) ? 0x0002u : 0u;
        mb |= (pe2  != pe1 ) ? 0x0004u : 0u;
        mb |= (pe3  != pe2 ) ? 0x0008u : 0u;
        mb |= (c0.x != pe3 ) ? 0x0010u : 0u;
        mb |= (c0.y != c0.x) ? 0x0020u : 0u;
        mb |= (c0.z != c0.y) ? 0x0040u : 0u;
        mb |= (c0.w != c0.z) ? 0x0080u : 0u;
        mb |= (c1.x != c0.w) ? 0x0100u : 0u;
        mb |= (c1.y != c1.x) ? 0x0200u : 0u;
        mb |= (c1.z != c1.y) ? 0x0400u : 0u;
        mb |= (c1.w != c1.z) ? 0x0800u : 0u;
        mb |= (ne0  != c1.w) ? 0x1000u : 0u;
        mb |= (ne1  != ne0 ) ? 0x2000u : 0u;
        mb |= (ne2  != ne1 ) ? 0x4000u : 0u;

        // zero bits for j >= T (row end; reference pads window with 0)
        const int L = T_DIM + 3 - e;   // max valid k
        const unsigned keep = (L >= 14) ? 0x7FFFu
                            : ((L >= 0) ? ((2u << L) - 1u) : 0u);
        mb &= keep;

        // windowed OR: o[k] = OR mb[k..k+6]; boundary for elem ii = bit (ii+1)
        unsigned o = mb | (mb >> 1);
        o |= o >> 2;
        o |= o >> 3;

        const int nvld = T_DIM - e;    // # valid elems for this lane

        auto elem = [&](int ii, float x, float mraw, int tg) {
            const float mm   = (ii < nvld) ? mraw : 0.0f;
            const float posf = (((float)tg) > 0.5f) ? 1.0f : 0.0f;
            const float smoothed = fmaf(posf, 0.95f, 0.025f);
            const float alpha_w  = fmaf(posf, -0.5f, 0.75f);
            const float bf = (float)((o >> (ii + 1)) & 1u);
            const float w  = fmaf(bf, 4.0f, 1.0f);

            const float ea   = __expf(-fabsf(x));
            const float opea = 1.0f + ea;
            const float r    = __builtin_amdgcn_rcpf(opea);
            const float adaptive = 1.5f - r;   // 1 - (sigmoid(|x|) - 0.5)

            const float bce = fmaf(-x, smoothed, fmaxf(x, 0.0f)) + __logf(opea);
            const float pt_ = __expf(-bce);
            const float om  = 1.0f - pt_;

            lsum = fmaf(alpha_w * om * om * bce * w * adaptive, mm, lsum);
            msum += mm;
        };

        elem(0, x0.x, m0.x, c0.x);
        elem(1, x0.y, m0.y, c0.y);
        elem(2, x0.z, m0.z, c0.z);
        elem(3, x0.w, m0.w, c0.w);
        elem(4, x1.x, m1.x, c1.x);
        elem(5, x1.y, m1.y, c1.y);
        elem(6, x1.z, m1.z, c1.z);
        elem(7, x1.w, m1.w, c1.w);

        if (!has) break;
        t = tn;
        d ^= 1;
    }

    // wave butterfly + block reduce
    #pragma unroll
    for (int off = 32; off > 0; off >>= 1) {
        lsum += __shfl_xor(lsum, off);
        msum += __shfl_xor(msum, off);
    }

    __shared__ float rL[4];
    __shared__ float rM[4];
    if (lane == 0) { rL[wv] = lsum; rM[wv] = msum; }
    __syncthreads();

    if (threadIdx.x == 0) {
        float bl = 0.0f, bm = 0.0f;
        #pragma unroll
        for (int i = 0; i < 4; ++i) { bl += rL[i]; bm += rM[i]; }
        partials[blockIdx.x] = make_float2(bl, bm);
    }
}

__global__ __launch_bounds__(BLOCK) void bfl_reduce(
    const float2* __restrict__ partials,
    float*        __restrict__ out)
{
    float ls = 0.0f, ms = 0.0f;
    #pragma unroll
    for (int i = 0; i < NUM_PARTIALS / BLOCK; ++i) {
        const float2 p = partials[i * BLOCK + threadIdx.x];
        ls += p.x; ms += p.y;
    }

    #pragma unroll
    for (int off = 32; off > 0; off >>= 1) {
        ls += __shfl_xor(ls, off);
        ms += __shfl_xor(ms, off);
    }

    __shared__ float sL[BLOCK / 64];
    __shared__ float sM[BLOCK / 64];
    const int wave = threadIdx.x >> 6;
    const int lane = threadIdx.x & 63;
    if (lane == 0) { sL[wave] = ls; sM[wave] = ms; }
    __syncthreads();

    if (threadIdx.x == 0) {
        float bl = 0.0f, bm = 0.0f;
        #pragma unroll
        for (int i = 0; i < BLOCK / 64; ++i) { bl += sL[i]; bm += sM[i]; }
        out[0] = (bm > 0.0f) ? (bl / bm) : 0.0f;
    }
}

extern "C" void kernel_launch(void* const* d_in, const int* in_sizes, int n_in,
                              void* d_out, int out_size, void* d_ws, size_t ws_size,
                              hipStream_t stream) {
    const float* inputs   = (const float*)d_in[0];
    const int*   targets  = (const int*)d_in[1];
    const float* mask     = (const float*)d_in[2];
    float*       out      = (float*)d_out;
    float2*      partials = (float2*)d_ws;

    bfl_main<<<GRID, BLOCK, 0, stream>>>(inputs, targets, mask, partials);
    bfl_reduce<<<1, BLOCK, 0, stream>>>(partials, out);
}

// Round 7
// 289.012 us; speedup vs baseline: 1.0185x; 1.0185x over previous
//
#include <hip/hip_runtime.h>
#include <math.h>

// BoundaryFocalLoss: B=128, T=200000, f32 inputs, i32 targets, f32 mask -> scalar f32.
// 307 MB irreducible read (3 x 4B/elem), ~50% served by L3 (restore-resident),
// ~50% by HBM (FETCH ~152 MB).
//
// R1: 654 us = same-address atomic serialization -> partials + 2nd kernel.
// R2-R6 ladder: four structurally different kernels (shallow reg loads / deep reg
//   MLP / reg double-buffer / async global_load_lds double-buffer, 2-56 cache
//   lines in flight per wave, occupancy 20-74%) ALL land at
//   dur ~= 307 MB / ~2.45 TB/s (119.5-126 us kernel time). Occupancy, VGPR count,
//   and in-flight depth each moved as designed; time never followed. Binding
//   resource: per-CU L2-miss service rate (~9.5 GB/s/CU ~= 4 B/cyc/CU on this
//   half-L3/half-HBM mix) — not reachable from source level.
// R7 (final): R3's empirically-fastest structure (2560 blocks, 8 elem/thread,
//   no launch-bounds cap) + validated VALU trims (window-OR boundary, rcp
//   adaptive). Expected at the wall: ~119 us kernel.

#define B_DIM 128
#define T_DIM 200000

constexpr int BLOCK           = 256;
constexpr int GROUPS_PER_ROW  = T_DIM / 4;          // 50000 int4/float4 groups
constexpr int CHUNKS_PER_ROW  = T_DIM / 8;          // 25000 8-elem chunks
constexpr int BLOCKS_X        = 20;                 // blocks per row
constexpr int ROW_STRIDE      = BLOCKS_X * BLOCK;   // 5120 chunks per sweep
constexpr int NUM_ITERS       = (CHUNKS_PER_ROW + ROW_STRIDE - 1) / ROW_STRIDE; // 5
constexpr int NUM_PARTIALS    = BLOCKS_X * B_DIM;   // 2560

__global__ __launch_bounds__(BLOCK) void bfl_main(
    const float* __restrict__ inputs,
    const int*   __restrict__ targets,
    const float* __restrict__ mask,
    float2*      __restrict__ partials)   // [NUM_PARTIALS] = (loss_sum, mask_sum)
{
    const int b = blockIdx.y;
    const long long row = (long long)b * T_DIM;
    const float4* __restrict__ inp4 = (const float4*)(inputs + row);
    const float4* __restrict__ msk4 = (const float4*)(mask + row);
    const int4*   __restrict__ tgt4 = (const int4*)(targets + row);

    float lsum = 0.0f, msum = 0.0f;

    #pragma unroll
    for (int iter = 0; iter < NUM_ITERS; ++iter) {
        const int chunk = iter * ROW_STRIDE + blockIdx.x * BLOCK + threadIdx.x;
        if (chunk < CHUNKS_PER_ROW) {
            const int q = chunk * 2;            // int4-group index

            const float4 x0 = inp4[q];
            const float4 x1 = inp4[q + 1];
            const float4 m0 = msk4[q];
            const float4 m1 = msk4[q + 1];
            const int4   c0 = tgt4[q];
            const int4   c1 = tgt4[q + 1];
            const int4   pv = (q > 0)
                ? tgt4[q - 1] : make_int4(c0.x, c0.x, c0.x, c0.x);
            const int4   nx = (q + 2 < GROUPS_PER_ROW)
                ? tgt4[q + 2] : make_int4(c1.w, c1.w, c1.w, c1.w);

            // tg[k] = targets[t0 - 4 + k], k = 0..14 (halo -4..+10).
            // Clamp-replication zeroes edge transition bits, matching the
            // reference's zero-padded trans[0] and 'SAME' window clipping.
            const int tg[15] = {pv.x, pv.y, pv.z, pv.w,
                                c0.x, c0.y, c0.z, c0.w,
                                c1.x, c1.y, c1.z, c1.w,
                                nx.x, nx.y, nx.z};

            unsigned mb = 0u;
            #pragma unroll
            for (int k = 1; k <= 14; ++k) {
                if (tg[k] != tg[k - 1]) mb |= (1u << k);
            }
            // windowed OR: o[k] = OR of mb[k..k+6]; boundary elem ii = bit (ii+1)
            unsigned o = mb | (mb >> 1);
            o |= o >> 2;
            o |= o >> 3;

            const float xs[8] = {x0.x, x0.y, x0.z, x0.w, x1.x, x1.y, x1.z, x1.w};
            const float ms[8] = {m0.x, m0.y, m0.z, m0.w, m1.x, m1.y, m1.z, m1.w};

            #pragma unroll
            for (int ii = 0; ii < 8; ++ii) {
                const float x  = xs[ii];
                const float mm = ms[ii];
                const float posf = (((float)tg[4 + ii]) > 0.5f) ? 1.0f : 0.0f;

                const float smoothed = fmaf(posf, 0.95f, 0.025f);  // pos*(1-ls)+ls/2
                const float alpha_w  = fmaf(posf, -0.5f, 0.75f);   // 0.25/0.75
                const float bf = (float)((o >> (ii + 1)) & 1u);
                const float w  = fmaf(bf, 4.0f, 1.0f);             // 1 or 5

                // ea = exp(-|x|); sigmoid(|x|) = 1/(1+ea);
                // adaptive = 1 - (sigmoid(|x|) - 0.5) = 1.5 - 1/(1+ea)
                const float ea   = __expf(-fabsf(x));
                const float opea = 1.0f + ea;
                const float r    = __builtin_amdgcn_rcpf(opea);
                const float adaptive = 1.5f - r;

                const float bce = fmaf(-x, smoothed, fmaxf(x, 0.0f)) + __logf(opea);
                const float pt  = __expf(-bce);
                const float om  = 1.0f - pt;

                lsum = fmaf(alpha_w * om * om * bce * w * adaptive, mm, lsum);
                msum += mm;
            }
        }
    }

    // wave (64-lane) butterfly reduction
    #pragma unroll
    for (int off = 32; off > 0; off >>= 1) {
        lsum += __shfl_xor(lsum, off);
        msum += __shfl_xor(msum, off);
    }

    __shared__ float sL[BLOCK / 64];
    __shared__ float sM[BLOCK / 64];
    const int wave = threadIdx.x >> 6;
    const int lane = threadIdx.x & 63;
    if (lane == 0) { sL[wave] = lsum; sM[wave] = msum; }
    __syncthreads();

    if (threadIdx.x == 0) {
        float bl = 0.0f, bm = 0.0f;
        #pragma unroll
        for (int i = 0; i < BLOCK / 64; ++i) { bl += sL[i]; bm += sM[i]; }
        partials[blockIdx.y * BLOCKS_X + blockIdx.x] = make_float2(bl, bm);
    }
}

__global__ __launch_bounds__(BLOCK) void bfl_reduce(
    const float2* __restrict__ partials,
    float*        __restrict__ out)
{
    float ls = 0.0f, ms = 0.0f;
    #pragma unroll
    for (int i = 0; i < NUM_PARTIALS / BLOCK; ++i) {
        const float2 p = partials[i * BLOCK + threadIdx.x];
        ls += p.x; ms += p.y;
    }

    #pragma unroll
    for (int off = 32; off > 0; off >>= 1) {
        ls += __shfl_xor(ls, off);
        ms += __shfl_xor(ms, off);
    }

    __shared__ float sL[BLOCK / 64];
    __shared__ float sM[BLOCK / 64];
    const int wave = threadIdx.x >> 6;
    const int lane = threadIdx.x & 63;
    if (lane == 0) { sL[wave] = ls; sM[wave] = ms; }
    __syncthreads();

    if (threadIdx.x == 0) {
        float bl = 0.0f, bm = 0.0f;
        #pragma unroll
        for (int i = 0; i < BLOCK / 64; ++i) { bl += sL[i]; bm += sM[i]; }
        out[0] = (bm > 0.0f) ? (bl / bm) : 0.0f;
    }
}

extern "C" void kernel_launch(void* const* d_in, const int* in_sizes, int n_in,
                              void* d_out, int out_size, void* d_ws, size_t ws_size,
                              hipStream_t stream) {
    const float* inputs   = (const float*)d_in[0];
    const int*   targets  = (const int*)d_in[1];
    const float* mask     = (const float*)d_in[2];
    float*       out      = (float*)d_out;
    float2*      partials = (float2*)d_ws;

    dim3 grid(BLOCKS_X, B_DIM);
    bfl_main<<<grid, BLOCK, 0, stream>>>(inputs, targets, mask, partials);
    bfl_reduce<<<1, BLOCK, 0, stream>>>(partials, out);
}